// Round 3
// baseline (268.803 us; speedup 1.0000x reference)
//
#include <hip/hip_runtime.h>

typedef unsigned int uint;
typedef unsigned short ushort;
using short8 = __attribute__((ext_vector_type(8))) short;   // 8 bf16 (4 VGPRs)
using f32x4  = __attribute__((ext_vector_type(4))) float;

#define NHALF 2048
#define DIM   1024
#define MROWS 4096
#define KMED  8388607u
#define NTRI  528            // 32*33/2 lower-triangle 128x128 blocks

// workspace layout (bytes)
#define L2_OFF   0ull                          // 64 MB f32 (lower blocks valid only)
#define AH_OFF   67108864ull                   // 8 MB bf16 hi
#define AL_OFF   (AH_OFF + 8388608ull)         // 8 MB bf16 lo
#define SQ_OFF   (AL_OFF + 8388608ull)         // 16 KB sq norms
#define GHA_OFF  (SQ_OFF + 16384ull)           // 64 KB: 16384-bin hist of bits 30:17
#define GHB_OFF  (GHA_OFF + 65536ull)          // 512 KB: 131072-bin hist of bits 16:0
#define SEL_OFF  (GHB_OFF + 524288ull)         // 64 B
#define ACC_OFF  (SEL_OFF + 64ull)             // 16 B

// ---------------------------------------------------------------- f32 -> bf16 hi/lo split + sqnorm
__device__ __forceinline__ ushort f2bf(float x) {
    uint u = __float_as_uint(x);
    u += 0x7FFFu + ((u >> 16) & 1u);           // RNE
    return (ushort)(u >> 16);
}

__global__ __launch_bounds__(256) void convert_kernel(const float* __restrict__ src,
                                                      const float* __restrict__ tgt,
                                                      ushort* __restrict__ ah,
                                                      ushort* __restrict__ al,
                                                      float* __restrict__ sq) {
    int row = blockIdx.x;
    const float* p = (row < NHALF) ? src + (size_t)row * DIM
                                   : tgt + (size_t)(row - NHALF) * DIM;
    int t = threadIdx.x;
    float4 v = reinterpret_cast<const float4*>(p)[t];
    float xs[4] = {v.x, v.y, v.z, v.w};
    ushort hh[4], ll[4];
    float s = 0.0f;
#pragma unroll
    for (int e = 0; e < 4; ++e) {
        float x = xs[e];
        s += x * x;
        ushort hb = f2bf(x);
        float hf = __uint_as_float(((uint)hb) << 16);
        ll[e] = f2bf(x - hf);
        hh[e] = hb;
    }
    ushort4 h4; h4.x = hh[0]; h4.y = hh[1]; h4.z = hh[2]; h4.w = hh[3];
    ushort4 l4; l4.x = ll[0]; l4.y = ll[1]; l4.z = ll[2]; l4.w = ll[3];
    reinterpret_cast<ushort4*>(ah + (size_t)row * DIM)[t] = h4;
    reinterpret_cast<ushort4*>(al + (size_t)row * DIM)[t] = l4;
    for (int o = 32; o; o >>= 1) s += __shfl_down(s, o);
    __shared__ float red[4];
    if ((t & 63) == 0) red[t >> 6] = s;
    __syncthreads();
    if (t == 0) sq[row] = red[0] + red[1] + red[2] + red[3];
}

// ---------------------------------------------------------------- MFMA GEMM (bf16-split, hi*(hi+lo)), 2-phase pipelined
// stage chunk cidx (16 rows x 32 cols = 1KB) of [buf][arr] from srcp row-block rb at k-offset kk0
#define STAGE1(buf, arr, srcp, rb, cidx) do {                                              \
    int _i = (cidx) * 64 + lane;                                                           \
    const ushort* _g = (srcp) + ((size_t)((rb) + (_i >> 2)) * DIM + kk0 + (_i & 3) * 8);   \
    __builtin_amdgcn_global_load_lds(                                                      \
        (const __attribute__((address_space(1))) uint*)_g,                                 \
        (__attribute__((address_space(3))) uint*)(&lds[buf][arr][0][0] + (size_t)(cidx) * 512), \
        16, 0, 0);                                                                         \
} while (0)

__global__ __launch_bounds__(256) void gemm_kernel(const ushort* __restrict__ ah,
                                                   const ushort* __restrict__ al,
                                                   const float* __restrict__ sq,
                                                   float* __restrict__ L2,
                                                   uint* __restrict__ ghist) {
    // XCD swizzle (528 = 8*66, bijective) then triangular decode
    int b = (int)blockIdx.x;
    b = (b & 7) * 66 + (b >> 3);
    int bi = (int)((sqrtf(8.0f * (float)b + 1.0f) - 1.0f) * 0.5f);
    while ((bi + 1) * (bi + 2) / 2 <= b) ++bi;
    while (bi * (bi + 1) / 2 > b) --bi;
    int bj = b - bi * (bi + 1) / 2;          // bj <= bi

    // [buf][0]=A-hi rows, [buf][1]=B-hi cols, [buf][2]=B-lo cols  (48 KB)
    __shared__ __align__(16) ushort lds[2][3][128][32];

    int t = threadIdx.x;
    int lane = t & 63, wid = t >> 6;
    int wm = wid >> 1, wn = wid & 1;         // 2x2 wave grid, 64x64 per wave
    int rowbase = bi * 128, colbase = bj * 128;

    f32x4 acc[4][4] = {};
    int fr = lane & 15, fk = (lane >> 4) * 8;

    // prologue: stage k-tile 0 into buffer 0
    {
        int kk0 = 0;
        STAGE1(0, 0, ah, rowbase, wid * 2); STAGE1(0, 0, ah, rowbase, wid * 2 + 1);
        STAGE1(0, 1, ah, colbase, wid * 2); STAGE1(0, 1, ah, colbase, wid * 2 + 1);
        STAGE1(0, 2, al, colbase, wid * 2); STAGE1(0, 2, al, colbase, wid * 2 + 1);
    }
    __syncthreads();

    int cur = 0;
    for (int kt = 0; kt < 32; ++kt) {
        if (kt < 31) {                        // issue next-tile loads BEFORE compute
            int kk0 = (kt + 1) * 32;
            int nb = cur ^ 1;
            STAGE1(nb, 0, ah, rowbase, wid * 2); STAGE1(nb, 0, ah, rowbase, wid * 2 + 1);
            STAGE1(nb, 1, ah, colbase, wid * 2); STAGE1(nb, 1, ah, colbase, wid * 2 + 1);
            STAGE1(nb, 2, al, colbase, wid * 2); STAGE1(nb, 2, al, colbase, wid * 2 + 1);
        }
        short8 fa[4], fbh[4], fbl[4];
#pragma unroll
        for (int m = 0; m < 4; ++m)
            fa[m] = *reinterpret_cast<const short8*>(&lds[cur][0][wm * 64 + m * 16 + fr][fk]);
#pragma unroll
        for (int n = 0; n < 4; ++n) {
            fbh[n] = *reinterpret_cast<const short8*>(&lds[cur][1][wn * 64 + n * 16 + fr][fk]);
            fbl[n] = *reinterpret_cast<const short8*>(&lds[cur][2][wn * 64 + n * 16 + fr][fk]);
        }
#pragma unroll
        for (int m = 0; m < 4; ++m)
#pragma unroll
            for (int n = 0; n < 4; ++n) {
                acc[m][n] = __builtin_amdgcn_mfma_f32_16x16x32_bf16(fa[m], fbh[n], acc[m][n], 0, 0, 0);
                acc[m][n] = __builtin_amdgcn_mfma_f32_16x16x32_bf16(fa[m], fbl[n], acc[m][n], 0, 0, 0);
            }
        __syncthreads();                      // drains next-tile vmcnt + this tile's readers
        cur ^= 1;
    }

    // ---- epilogue: L2 store + fused 16384-bin hist of bits 30:17 (u16-packed in LDS)
    uint* h = (uint*)lds;                     // 8192 words = 32 KB
    for (int i = t; i < 8192; i += 256) h[i] = 0;
    __syncthreads();

    uint w = (bi == bj) ? 1u : 2u;
    int fq = lane >> 4;
#pragma unroll
    for (int m = 0; m < 4; ++m) {
#pragma unroll
        for (int n = 0; n < 4; ++n) {
            int gj = colbase + wn * 64 + n * 16 + fr;
            float sqj = sq[gj];
#pragma unroll
            for (int r = 0; r < 4; ++r) {
                int gi = rowbase + wm * 64 + m * 16 + fq * 4 + r;
                float v = fmaxf(sq[gi] + sqj - 2.0f * acc[m][n][r], 0.0f);
                L2[(size_t)gi * MROWS + gj] = v;
                uint k14 = __float_as_uint(v) >> 17;      // <16384 always (bit31==0)
                atomicAdd(&h[k14 >> 1], (k14 & 1) ? (w << 16) : w);
            }
        }
    }
    __syncthreads();
    for (int i = t; i < 8192; i += 256) {      // flush nonzero bins to global
        uint wd = h[i];
        if (wd) {
            uint lo = wd & 0xFFFFu, hi2 = wd >> 16;
            if (lo)  atomicAdd(&ghist[2 * i],     lo);
            if (hi2) atomicAdd(&ghist[2 * i + 1], hi2);
        }
    }
}

// ---------------------------------------------------------------- select1: scan 16384 bins -> 14-bit prefix + k'
__global__ __launch_bounds__(256) void select1_kernel(const uint* __restrict__ gh,
                                                      uint* __restrict__ sel) {
    __shared__ uint part[256];
    __shared__ uint loc[2];
    __shared__ uint bins[64];
    int t = threadIdx.x;
    uint s = 0;
    for (int i = 0; i < 64; ++i) s += gh[t * 64 + i];
    part[t] = s;
    __syncthreads();
    if (t == 0) {
        uint k = KMED, cum = 0; int seg = 0;
        for (; seg < 256; ++seg) { uint c = part[seg]; if (cum + c > k) break; cum += c; }
        loc[0] = (uint)seg; loc[1] = k - cum;
    }
    __syncthreads();
    int seg = (int)loc[0];
    if (t < 64) bins[t] = gh[seg * 64 + t];
    __syncthreads();
    if (t == 0) {
        uint k = loc[1], cum = 0; int bb = 0;
        for (; bb < 64; ++bb) { uint c = bins[bb]; if (cum + c > k) break; cum += c; }
        sel[0] = (uint)(seg * 64 + bb);        // bits 30:17 of median
        sel[1] = k - cum;                      // rank within that bin
    }
}

// ---------------------------------------------------------------- histB: filtered hist of low 17 bits
__global__ __launch_bounds__(256) void histb_kernel(const float* __restrict__ L2,
                                                    const uint* __restrict__ sel,
                                                    uint* __restrict__ ghb) {
    uint p14 = sel[0];
    for (int row = blockIdx.x; row < MROWS; row += gridDim.x) {
        int nc = ((row >> 7) + 1) << 7;        // valid cols (through diag block)
        int diaglo = (row >> 7) << 7;
        const float4* rp = reinterpret_cast<const float4*>(L2 + (size_t)row * MROWS);
        for (int q = threadIdx.x; q < (nc >> 2); q += 256) {
            float4 v = rp[q];
            uint w = ((q << 2) >= diaglo) ? 1u : 2u;
            uint bb[4] = {__float_as_uint(v.x), __float_as_uint(v.y),
                          __float_as_uint(v.z), __float_as_uint(v.w)};
#pragma unroll
            for (int e = 0; e < 4; ++e)
                if ((bb[e] >> 17) == p14)
                    atomicAdd(&ghb[bb[e] & 0x1FFFFu], w);
        }
    }
}

// ---------------------------------------------------------------- select2: scan 131072 bins -> exact median, bandwidth
__global__ __launch_bounds__(256) void select2_kernel(const uint* __restrict__ ghb,
                                                      uint* __restrict__ sel,
                                                      float* __restrict__ out) {
    __shared__ uint seg4[128][4];
    __shared__ uint lin[1024];
    __shared__ uint loc[2];
    int t = threadIdx.x, lane = t & 63, wv = t >> 6;
    for (int i = 0; i < 128; ++i) {            // segment i = bins [i*1024, i*1024+1024)
        uint4 v = reinterpret_cast<const uint4*>(ghb)[i * 256 + t];
        uint s = v.x + v.y + v.z + v.w;
        for (int o = 32; o; o >>= 1) s += __shfl_down(s, o);
        if (lane == 0) seg4[i][wv] = s;
    }
    __syncthreads();
    if (t == 0) {
        uint k = sel[1], cum = 0; int seg = 0;
        for (; seg < 128; ++seg) {
            uint c = seg4[seg][0] + seg4[seg][1] + seg4[seg][2] + seg4[seg][3];
            if (cum + c > k) break; cum += c;
        }
        loc[0] = (uint)seg; loc[1] = k - cum;
    }
    __syncthreads();
    int seg = (int)loc[0];
    {
        uint4 v = reinterpret_cast<const uint4*>(ghb)[seg * 256 + t];
        lin[t * 4 + 0] = v.x; lin[t * 4 + 1] = v.y; lin[t * 4 + 2] = v.z; lin[t * 4 + 3] = v.w;
    }
    __syncthreads();
    if (t == 0) {
        uint k = loc[1], cum = 0; int bb = 0;
        for (; bb < 1024; ++bb) { uint c = lin[bb]; if (cum + c > k) break; cum += c; }
        uint mbits = (sel[0] << 17) | (uint)(seg * 1024 + bb);
        float median = __uint_as_float(mbits);
        float logn = logf(2048.0f + 1e-8f);
        float bw = sqrtf(0.5f * median / logn);
        out[1] = bw;                                       // bandwidth
        reinterpret_cast<float*>(sel)[2] = logn / median;  // 1/(2 bw^2)
    }
}

// ---------------------------------------------------------------- loss reduce over triangle (weighted)
__global__ __launch_bounds__(256) void loss_kernel(const float* __restrict__ L2,
                                                   const float* __restrict__ selF,
                                                   double* __restrict__ acc) {
    float itb = selF[2];                       // 1/(2 bw^2)
    int t = threadIdx.x;
    float local = 0.0f;
    for (int row = blockIdx.x; row < MROWS; row += gridDim.x) {
        int nc = ((row >> 7) + 1) << 7;
        int diaglo = (row >> 7) << 7;
        bool rlow = row < NHALF;
        const float4* rp = reinterpret_cast<const float4*>(L2 + (size_t)row * MROWS);
        for (int q = t; q < (nc >> 2); q += 256) {
            float4 v = rp[q];
            int j0 = q << 2;
            float w = (j0 >= diaglo) ? 1.0f : 2.0f;
            float sgn = ((j0 < NHALF) == rlow) ? w : -w;   // NHALF is 128-block aligned
            float s = __expf(-v.x * itb) + __expf(-v.y * itb) +
                      __expf(-v.z * itb) + __expf(-v.w * itb);
            local += sgn * s;
        }
    }
    for (int o = 32; o; o >>= 1) local += __shfl_down(local, o);
    __shared__ float red[4];
    if ((t & 63) == 0) red[t >> 6] = local;
    __syncthreads();
    if (t == 0) atomicAdd(acc, (double)(red[0] + red[1] + red[2] + red[3]));
}

__global__ void finalize_kernel(const double* __restrict__ acc, float* __restrict__ out) {
    out[0] = (float)(acc[0] / 4194304.0);      // mean over N*N, N=2048
}

// ---------------------------------------------------------------- launch
extern "C" void kernel_launch(void* const* d_in, const int* in_sizes, int n_in,
                              void* d_out, int out_size, void* d_ws, size_t ws_size,
                              hipStream_t stream) {
    const float* src = (const float*)d_in[0];
    const float* tgt = (const float*)d_in[1];
    float* out = (float*)d_out;
    char* ws = (char*)d_ws;
    float*  L2   = (float*)(ws + L2_OFF);
    ushort* ahp  = (ushort*)(ws + AH_OFF);
    ushort* alp  = (ushort*)(ws + AL_OFF);
    float*  sq   = (float*)(ws + SQ_OFF);
    uint*   gha  = (uint*)(ws + GHA_OFF);
    uint*   ghb  = (uint*)(ws + GHB_OFF);
    uint*   sel  = (uint*)(ws + SEL_OFF);
    double* acc  = (double*)(ws + ACC_OFF);

    // zero histA (64KB) + histB (512KB) + sel (64B) + acc (16B)
    hipMemsetAsync(ws + GHA_OFF, 0, 65536 + 524288 + 64 + 16, stream);

    convert_kernel<<<MROWS, 256, 0, stream>>>(src, tgt, ahp, alp, sq);
    gemm_kernel<<<NTRI, 256, 0, stream>>>(ahp, alp, sq, L2, gha);
    select1_kernel<<<1, 256, 0, stream>>>(gha, sel);
    histb_kernel<<<2048, 256, 0, stream>>>(L2, sel, ghb);
    select2_kernel<<<1, 256, 0, stream>>>(ghb, sel, out);
    loss_kernel<<<2048, 256, 0, stream>>>(L2, (const float*)sel, acc);
    finalize_kernel<<<1, 1, 0, stream>>>(acc, out);
}

// Round 4
// 205.338 us; speedup vs baseline: 1.3091x; 1.3091x over previous
//
#include <hip/hip_runtime.h>

typedef unsigned int uint;
typedef unsigned short ushort;
using short8 = __attribute__((ext_vector_type(8))) short;   // 8 bf16 (4 VGPRs)
using f32x4  = __attribute__((ext_vector_type(4))) float;

#define NHALF 2048
#define DIM   1024
#define MROWS 4096
#define KMED  8388607u
#define NTRI  528            // 32*33/2 lower-triangle 128x128 blocks

// workspace layout (bytes)
#define L2_OFF   0ull                          // 64 MB f32 (lower blocks valid only)
#define AH_OFF   67108864ull                   // 8 MB bf16 hi
#define AL_OFF   (AH_OFF + 8388608ull)         // 8 MB bf16 lo
#define SQ_OFF   (AL_OFF + 8388608ull)         // 16 KB sq norms
#define GHA_OFF  (SQ_OFF + 16384ull)           // 64 KB: 16384-bin hist of bits 30:17
#define GHB_OFF  (GHA_OFF + 65536ull)          // 512 KB: 131072-bin hist of bits 16:0
#define SEL_OFF  (GHB_OFF + 524288ull)         // 64 B
#define ACC_OFF  (SEL_OFF + 64ull)             // 16 B

// ---------------------------------------------------------------- f32 -> bf16 hi/lo split + sqnorm
__device__ __forceinline__ ushort f2bf(float x) {
    uint u = __float_as_uint(x);
    u += 0x7FFFu + ((u >> 16) & 1u);           // RNE
    return (ushort)(u >> 16);
}

__global__ __launch_bounds__(256) void convert_kernel(const float* __restrict__ src,
                                                      const float* __restrict__ tgt,
                                                      ushort* __restrict__ ah,
                                                      ushort* __restrict__ al,
                                                      float* __restrict__ sq) {
    int row = blockIdx.x;
    const float* p = (row < NHALF) ? src + (size_t)row * DIM
                                   : tgt + (size_t)(row - NHALF) * DIM;
    int t = threadIdx.x;
    float4 v = reinterpret_cast<const float4*>(p)[t];
    float xs[4] = {v.x, v.y, v.z, v.w};
    ushort hh[4], ll[4];
    float s = 0.0f;
#pragma unroll
    for (int e = 0; e < 4; ++e) {
        float x = xs[e];
        s += x * x;
        ushort hb = f2bf(x);
        float hf = __uint_as_float(((uint)hb) << 16);
        ll[e] = f2bf(x - hf);
        hh[e] = hb;
    }
    ushort4 h4; h4.x = hh[0]; h4.y = hh[1]; h4.z = hh[2]; h4.w = hh[3];
    ushort4 l4; l4.x = ll[0]; l4.y = ll[1]; l4.z = ll[2]; l4.w = ll[3];
    reinterpret_cast<ushort4*>(ah + (size_t)row * DIM)[t] = h4;
    reinterpret_cast<ushort4*>(al + (size_t)row * DIM)[t] = l4;
    for (int o = 32; o; o >>= 1) s += __shfl_down(s, o);
    __shared__ float red[4];
    if ((t & 63) == 0) red[t >> 6] = s;
    __syncthreads();
    if (t == 0) sq[row] = red[0] + red[1] + red[2] + red[3];
}

// ---------------------------------------------------------------- MFMA GEMM (bf16-split, hi*(hi+lo)), 2-phase pipelined
#define STAGE1(buf, arr, srcp, rb, cidx) do {                                              \
    int _i = (cidx) * 64 + lane;                                                           \
    const ushort* _g = (srcp) + ((size_t)((rb) + (_i >> 2)) * DIM + kk0 + (_i & 3) * 8);   \
    __builtin_amdgcn_global_load_lds(                                                      \
        (const __attribute__((address_space(1))) uint*)_g,                                 \
        (__attribute__((address_space(3))) uint*)(&lds[buf][arr][0][0] + (size_t)(cidx) * 512), \
        16, 0, 0);                                                                         \
} while (0)

__global__ __launch_bounds__(256) void gemm_kernel(const ushort* __restrict__ ah,
                                                   const ushort* __restrict__ al,
                                                   const float* __restrict__ sq,
                                                   float* __restrict__ L2,
                                                   uint* __restrict__ ghist) {
    // XCD swizzle (528 = 8*66, bijective) then triangular decode
    int b = (int)blockIdx.x;
    b = (b & 7) * 66 + (b >> 3);
    int bi = (int)((sqrtf(8.0f * (float)b + 1.0f) - 1.0f) * 0.5f);
    while ((bi + 1) * (bi + 2) / 2 <= b) ++bi;
    while (bi * (bi + 1) / 2 > b) --bi;
    int bj = b - bi * (bi + 1) / 2;          // bj <= bi

    // [buf][0]=A-hi rows, [buf][1]=B-hi cols, [buf][2]=B-lo cols  (48 KB)
    __shared__ __align__(16) ushort lds[2][3][128][32];

    int t = threadIdx.x;
    int lane = t & 63, wid = t >> 6;
    int wm = wid >> 1, wn = wid & 1;         // 2x2 wave grid, 64x64 per wave
    int rowbase = bi * 128, colbase = bj * 128;

    f32x4 acc[4][4] = {};
    int fr = lane & 15, fk = (lane >> 4) * 8;

    // prologue: stage k-tile 0 into buffer 0
    {
        int kk0 = 0;
        STAGE1(0, 0, ah, rowbase, wid * 2); STAGE1(0, 0, ah, rowbase, wid * 2 + 1);
        STAGE1(0, 1, ah, colbase, wid * 2); STAGE1(0, 1, ah, colbase, wid * 2 + 1);
        STAGE1(0, 2, al, colbase, wid * 2); STAGE1(0, 2, al, colbase, wid * 2 + 1);
    }
    __syncthreads();

    int cur = 0;
    for (int kt = 0; kt < 32; ++kt) {
        if (kt < 31) {                        // issue next-tile loads BEFORE compute
            int kk0 = (kt + 1) * 32;
            int nb = cur ^ 1;
            STAGE1(nb, 0, ah, rowbase, wid * 2); STAGE1(nb, 0, ah, rowbase, wid * 2 + 1);
            STAGE1(nb, 1, ah, colbase, wid * 2); STAGE1(nb, 1, ah, colbase, wid * 2 + 1);
            STAGE1(nb, 2, al, colbase, wid * 2); STAGE1(nb, 2, al, colbase, wid * 2 + 1);
        }
        short8 fa[4], fbh[4], fbl[4];
#pragma unroll
        for (int m = 0; m < 4; ++m)
            fa[m] = *reinterpret_cast<const short8*>(&lds[cur][0][wm * 64 + m * 16 + fr][fk]);
#pragma unroll
        for (int n = 0; n < 4; ++n) {
            fbh[n] = *reinterpret_cast<const short8*>(&lds[cur][1][wn * 64 + n * 16 + fr][fk]);
            fbl[n] = *reinterpret_cast<const short8*>(&lds[cur][2][wn * 64 + n * 16 + fr][fk]);
        }
#pragma unroll
        for (int m = 0; m < 4; ++m)
#pragma unroll
            for (int n = 0; n < 4; ++n) {
                acc[m][n] = __builtin_amdgcn_mfma_f32_16x16x32_bf16(fa[m], fbh[n], acc[m][n], 0, 0, 0);
                acc[m][n] = __builtin_amdgcn_mfma_f32_16x16x32_bf16(fa[m], fbl[n], acc[m][n], 0, 0, 0);
            }
        __syncthreads();                      // drains next-tile vmcnt + this tile's readers
        cur ^= 1;
    }

    // ---- epilogue: L2 store + fused 16384-bin hist of bits 30:17 (u16-packed in LDS)
    uint* h = (uint*)lds;                     // 8192 words = 32 KB
    for (int i = t; i < 8192; i += 256) h[i] = 0;
    __syncthreads();

    uint w = (bi == bj) ? 1u : 2u;
    int fq = lane >> 4;
#pragma unroll
    for (int m = 0; m < 4; ++m) {
#pragma unroll
        for (int n = 0; n < 4; ++n) {
            int gj = colbase + wn * 64 + n * 16 + fr;
            float sqj = sq[gj];
#pragma unroll
            for (int r = 0; r < 4; ++r) {
                int gi = rowbase + wm * 64 + m * 16 + fq * 4 + r;
                float v = fmaxf(sq[gi] + sqj - 2.0f * acc[m][n][r], 0.0f);
                L2[(size_t)gi * MROWS + gj] = v;
                uint k14 = __float_as_uint(v) >> 17;      // <16384 always (bit31==0)
                atomicAdd(&h[k14 >> 1], (k14 & 1) ? (w << 16) : w);
            }
        }
    }
    __syncthreads();
    for (int i = t; i < 8192; i += 256) {      // flush nonzero bins to global
        uint wd = h[i];
        if (wd) {
            uint lo = wd & 0xFFFFu, hi2 = wd >> 16;
            if (lo)  atomicAdd(&ghist[2 * i],     lo);
            if (hi2) atomicAdd(&ghist[2 * i + 1], hi2);
        }
    }
}

// ---------------------------------------------------------------- select1: 16384 bins -> 14-bit prefix + rank
// parallel: thread t sums bins [t*64, t*64+64) via 16 independent uint4 loads
__global__ __launch_bounds__(256) void select1_kernel(const uint* __restrict__ gh,
                                                      uint* __restrict__ sel) {
    __shared__ uint part[256];
    __shared__ uint loc[2];
    __shared__ uint lin[64];
    int t = threadIdx.x;
    const uint4* p = reinterpret_cast<const uint4*>(gh);   // 4096 uint4
    uint s = 0;
#pragma unroll
    for (int i = 0; i < 16; ++i) {
        uint4 v = p[t * 16 + i];
        s += v.x + v.y + v.z + v.w;
    }
    part[t] = s;
    __syncthreads();
    if (t == 0) {
        uint k = KMED, cum = 0; int seg = 0;
        for (; seg < 256; ++seg) { uint c = part[seg]; if (cum + c > k) break; cum += c; }
        loc[0] = (uint)seg; loc[1] = k - cum;
    }
    __syncthreads();
    int seg = (int)loc[0];
    if (t < 16) {
        uint4 v = p[seg * 16 + t];
        lin[t * 4 + 0] = v.x; lin[t * 4 + 1] = v.y; lin[t * 4 + 2] = v.z; lin[t * 4 + 3] = v.w;
    }
    __syncthreads();
    if (t == 0) {
        uint k = loc[1], cum = 0; int bb = 0;
        for (; bb < 64; ++bb) { uint c = lin[bb]; if (cum + c > k) break; cum += c; }
        sel[0] = (uint)(seg * 64 + bb);        // bits 30:17 of median
        sel[1] = k - cum;                      // rank within that bin
    }
}

// ---------------------------------------------------------------- histB: filtered hist of low 17 bits
__global__ __launch_bounds__(256) void histb_kernel(const float* __restrict__ L2,
                                                    const uint* __restrict__ sel,
                                                    uint* __restrict__ ghb) {
    uint p14 = sel[0];
    for (int row = blockIdx.x; row < MROWS; row += gridDim.x) {
        int nc = ((row >> 7) + 1) << 7;        // valid cols (through diag block)
        int diaglo = (row >> 7) << 7;
        const float4* rp = reinterpret_cast<const float4*>(L2 + (size_t)row * MROWS);
        for (int q = threadIdx.x; q < (nc >> 2); q += 256) {
            float4 v = rp[q];
            uint w = ((q << 2) >= diaglo) ? 1u : 2u;
            uint bb[4] = {__float_as_uint(v.x), __float_as_uint(v.y),
                          __float_as_uint(v.z), __float_as_uint(v.w)};
#pragma unroll
            for (int e = 0; e < 4; ++e)
                if ((bb[e] >> 17) == p14)
                    atomicAdd(&ghb[bb[e] & 0x1FFFFu], w);
        }
    }
}

// ---------------------------------------------------------------- select2: 131072 bins -> exact median, bandwidth
// parallel: thread t sums bins [t*512, t*512+512) via 128 independent uint4 loads
__global__ __launch_bounds__(256) void select2_kernel(const uint* __restrict__ ghb,
                                                      uint* __restrict__ sel,
                                                      float* __restrict__ out) {
    __shared__ uint part[256];
    __shared__ uint loc[2];
    __shared__ uint lin[512];
    int t = threadIdx.x;
    const uint4* p = reinterpret_cast<const uint4*>(ghb);  // 32768 uint4
    uint s = 0;
#pragma unroll 8
    for (int i = 0; i < 128; ++i) {
        uint4 v = p[t * 128 + i];
        s += v.x + v.y + v.z + v.w;
    }
    part[t] = s;
    __syncthreads();
    if (t == 0) {
        uint k = sel[1], cum = 0; int seg = 0;
        for (; seg < 256; ++seg) { uint c = part[seg]; if (cum + c > k) break; cum += c; }
        loc[0] = (uint)seg; loc[1] = k - cum;
    }
    __syncthreads();
    int seg = (int)loc[0];
    if (t < 128) {
        uint4 v = p[seg * 128 + t];
        lin[t * 4 + 0] = v.x; lin[t * 4 + 1] = v.y; lin[t * 4 + 2] = v.z; lin[t * 4 + 3] = v.w;
    }
    __syncthreads();
    if (t == 0) {
        uint k = loc[1], cum = 0; int bb = 0;
        for (; bb < 512; ++bb) { uint c = lin[bb]; if (cum + c > k) break; cum += c; }
        uint mbits = (sel[0] << 17) | (uint)(seg * 512 + bb);
        float median = __uint_as_float(mbits);
        float logn = logf(2048.0f + 1e-8f);
        float bw = sqrtf(0.5f * median / logn);
        out[1] = bw;                                       // bandwidth
        reinterpret_cast<float*>(sel)[2] = logn / median;  // 1/(2 bw^2)
    }
}

// ---------------------------------------------------------------- loss reduce over triangle (weighted)
__global__ __launch_bounds__(256) void loss_kernel(const float* __restrict__ L2,
                                                   const float* __restrict__ selF,
                                                   double* __restrict__ acc) {
    float itb = selF[2];                       // 1/(2 bw^2)
    int t = threadIdx.x;
    float local = 0.0f;
    for (int row = blockIdx.x; row < MROWS; row += gridDim.x) {
        int nc = ((row >> 7) + 1) << 7;
        int diaglo = (row >> 7) << 7;
        bool rlow = row < NHALF;
        const float4* rp = reinterpret_cast<const float4*>(L2 + (size_t)row * MROWS);
        for (int q = t; q < (nc >> 2); q += 256) {
            float4 v = rp[q];
            int j0 = q << 2;
            float w = (j0 >= diaglo) ? 1.0f : 2.0f;
            float sgn = ((j0 < NHALF) == rlow) ? w : -w;   // NHALF is 128-block aligned
            float s = __expf(-v.x * itb) + __expf(-v.y * itb) +
                      __expf(-v.z * itb) + __expf(-v.w * itb);
            local += sgn * s;
        }
    }
    for (int o = 32; o; o >>= 1) local += __shfl_down(local, o);
    __shared__ float red[4];
    if ((t & 63) == 0) red[t >> 6] = local;
    __syncthreads();
    if (t == 0) atomicAdd(acc, (double)(red[0] + red[1] + red[2] + red[3]));
}

__global__ void finalize_kernel(const double* __restrict__ acc, float* __restrict__ out) {
    out[0] = (float)(acc[0] / 4194304.0);      // mean over N*N, N=2048
}

// ---------------------------------------------------------------- launch
extern "C" void kernel_launch(void* const* d_in, const int* in_sizes, int n_in,
                              void* d_out, int out_size, void* d_ws, size_t ws_size,
                              hipStream_t stream) {
    const float* src = (const float*)d_in[0];
    const float* tgt = (const float*)d_in[1];
    float* out = (float*)d_out;
    char* ws = (char*)d_ws;
    float*  L2   = (float*)(ws + L2_OFF);
    ushort* ahp  = (ushort*)(ws + AH_OFF);
    ushort* alp  = (ushort*)(ws + AL_OFF);
    float*  sq   = (float*)(ws + SQ_OFF);
    uint*   gha  = (uint*)(ws + GHA_OFF);
    uint*   ghb  = (uint*)(ws + GHB_OFF);
    uint*   sel  = (uint*)(ws + SEL_OFF);
    double* acc  = (double*)(ws + ACC_OFF);

    // zero histA (64KB) + histB (512KB) + sel (64B) + acc (16B)
    hipMemsetAsync(ws + GHA_OFF, 0, 65536 + 524288 + 64 + 16, stream);

    convert_kernel<<<MROWS, 256, 0, stream>>>(src, tgt, ahp, alp, sq);
    gemm_kernel<<<NTRI, 256, 0, stream>>>(ahp, alp, sq, L2, gha);
    select1_kernel<<<1, 256, 0, stream>>>(gha, sel);
    histb_kernel<<<2048, 256, 0, stream>>>(L2, sel, ghb);
    select2_kernel<<<1, 256, 0, stream>>>(ghb, sel, out);
    loss_kernel<<<2048, 256, 0, stream>>>(L2, (const float*)sel, acc);
    finalize_kernel<<<1, 1, 0, stream>>>(acc, out);
}